// Round 1
// baseline (735.310 us; speedup 1.0000x reference)
//
#include <hip/hip_runtime.h>
#include <hip/hip_bf16.h>
#include <math.h>

typedef short s8v  __attribute__((ext_vector_type(8)));   // 8 bf16 (MFMA A/B frag)
typedef float f4v  __attribute__((ext_vector_type(4)));   // MFMA C/D frag
typedef unsigned short ushort_t;

constexpr int IN_DIM_C = 2048;
constexpr int NEXP     = 64;
constexpr int MTILE    = 64;                // tokens per block: 4 waves x 16
constexpr int KC       = 32;                // K per MFMA chunk
constexpr int NCHUNK   = IN_DIM_C / KC;     // 64
constexpr int BROW     = 40;                // padded B row stride (ushorts) = 80 B -> slot stride 5 (mod 8), max 2-way
constexpr int BPLANE   = NEXP * BROW;       // 2560 ushorts per plane

// Round-to-nearest-even fp32 -> bf16 hi, then bf16(residual) -> lo.
__device__ __forceinline__ void split_bf16(float f, ushort_t& hi, ushort_t& lo) {
  unsigned u = __float_as_uint(f);
  unsigned r = u + 0x7FFFu + ((u >> 16) & 1u);
  hi = (ushort_t)(r >> 16);
  float hif = __uint_as_float(r & 0xFFFF0000u);   // exact bf16 value of hi
  float lof = f - hif;                             // exact residual in fp32
  unsigned ul = __float_as_uint(lof);
  unsigned rl = ul + 0x7FFFu + ((ul >> 16) & 1u);
  lo = (ushort_t)(rl >> 16);
}

// Pre-kernel: split W [64,2048] fp32 into bf16 hi/lo planes in d_ws (512 KB).
__global__ void conv_w_kernel(const float* __restrict__ W,
                              ushort_t* __restrict__ w_hi, ushort_t* __restrict__ w_lo) {
  const int i = blockIdx.x * 256 + threadIdx.x;   // grid covers 131072 exactly
  ushort_t h, l;
  split_bf16(W[i], h, l);
  w_hi[i] = h;
  w_lo[i] = l;
}

// v2: MTILE=64 (1 m-tile per wave), grid 1024 -> 4 blocks/CU, 16 waves/CU.
// B (w_hi/w_lo chunk) staged once per block per chunk into padded LDS (double-
// buffered, async-split: loads issued at loop top, ds_write after MFMA phase,
// one barrier per chunk). A loads direct-to-register with 1-chunk prefetch.
__global__ __launch_bounds__(256, 4)
void router_mfma(const float* __restrict__ x,
                 const ushort_t* __restrict__ w_hi, const ushort_t* __restrict__ w_lo,
                 float* __restrict__ out_idx, float* __restrict__ out_w,
                 float* __restrict__ out_p) {
  __shared__ __align__(16) ushort_t Bs[2][2 * BPLANE];   // [buf][plane*BPLANE + e*BROW + k] : 20 KB
  __shared__ float L[MTILE * 65 + MTILE];                // logits tile (stride 65) + 1/sum : 16.9 KB
  float* Sv = L + MTILE * 65;

  const int tid   = threadIdx.x;
  const int lane  = tid & 63;
  const int wave  = tid >> 6;        // 0..3
  const int row16 = lane & 15;       // M/N index within a 16-tile
  const int quad  = lane >> 4;       // 0..3, k-octet selector
  const int m0    = blockIdx.x * MTILE;

  // B staging assignment: thread covers expert se, k-quad sk, both planes (16 B each)
  const int se = tid >> 2;           // 0..63
  const int sk = tid & 3;            // 0..3
  const ushort_t* bsrc_h = w_hi + (size_t)se * IN_DIM_C + sk * 8;
  const ushort_t* bsrc_l = w_lo + (size_t)se * IN_DIM_C + sk * 8;
  const int bdst = se * BROW + sk * 8;

  // A: lane reads 8 contiguous fp32 of its token row at k = quad*8 (+chunk)
  const float* aptr = x + (size_t)(m0 + wave * 16 + row16) * IN_DIM_C + quad * 8;

  f4v acc[4];
#pragma unroll
  for (int nt = 0; nt < 4; ++nt) acc[nt] = (f4v){0.f, 0.f, 0.f, 0.f};

  // Prologue: stage chunk 0 into Bs[0]; load A chunk 0 into regs
  {
    s8v h0 = *(const s8v*)bsrc_h;
    s8v l0 = *(const s8v*)bsrc_l;
    *(s8v*)&Bs[0][bdst]          = h0;
    *(s8v*)&Bs[0][BPLANE + bdst] = l0;
  }
  float4 ar0 = *(const float4*)(aptr);
  float4 ar1 = *(const float4*)(aptr + 4);
  __syncthreads();

  int p = 0;
  for (int c = 0; c < NCHUNK; ++c) {
    // Issue next-chunk loads early (regs only; wave-uniform predicate)
    float4 an0, an1;
    s8v nh, nl;
    const bool more = (c + 1 < NCHUNK);
    if (more) {
      const int kn = (c + 1) * KC;
      an0 = *(const float4*)(aptr + kn);
      an1 = *(const float4*)(aptr + kn + 4);
      nh  = *(const s8v*)(bsrc_h + kn);
      nl  = *(const s8v*)(bsrc_l + kn);
    }

    // Convert current A chunk to hi/lo bf16 frags (VALU; overlaps load latency)
    s8v ah, al;
    {
      const float xv[8] = {ar0.x, ar0.y, ar0.z, ar0.w, ar1.x, ar1.y, ar1.z, ar1.w};
#pragma unroll
      for (int j = 0; j < 8; ++j) {
        ushort_t h, l;
        split_bf16(xv[j], h, l);
        ah[j] = (short)h;
        al[j] = (short)l;
      }
    }

    // 12 MFMAs: hh + hl + lh for each nt, B frags from padded LDS (2-way max conflicts)
    const ushort_t* bcur = &Bs[p][0];
#pragma unroll
    for (int nt = 0; nt < 4; ++nt) {
      const int off = (nt * 16 + row16) * BROW + quad * 8;
      s8v bh = *(const s8v*)(bcur + off);
      s8v bl = *(const s8v*)(bcur + BPLANE + off);
      acc[nt] = __builtin_amdgcn_mfma_f32_16x16x32_bf16(ah, bh, acc[nt], 0, 0, 0);
      acc[nt] = __builtin_amdgcn_mfma_f32_16x16x32_bf16(ah, bl, acc[nt], 0, 0, 0);
      acc[nt] = __builtin_amdgcn_mfma_f32_16x16x32_bf16(al, bh, acc[nt], 0, 0, 0);
    }

    // Write-late: commit next B chunk into the other buffer; rotate A regs
    if (more) {
      *(s8v*)&Bs[p ^ 1][bdst]          = nh;   // compiler inserts vmcnt wait here
      *(s8v*)&Bs[p ^ 1][BPLANE + bdst] = nl;
      ar0 = an0;
      ar1 = an1;
    }
    __syncthreads();   // (a) stage(c+1) visible for next iter; (b) reads of Bs[p] done before overwrite at c+2
    p ^= 1;
  }

  // Epilogue: scatter logits to LDS. C/D layout: col(expert)=lane&15, row(token)=quad*4+reg.
#pragma unroll
  for (int nt = 0; nt < 4; ++nt)
#pragma unroll
    for (int r = 0; r < 4; ++r) {
      const int tok = wave * 16 + quad * 4 + r;
      const int e   = nt * 16 + row16;
      L[tok * 65 + e] = acc[nt][r];
    }
  __syncthreads();

  if (tid < MTILE) {
    const int tok = tid;
    // Top-2 on raw logits (ties keep lower index, matching lax.top_k)
    float v1 = -1e30f, v2 = -1e30f;
    int i1 = 0, i2 = 0;
    for (int e = 0; e < NEXP; ++e) {
      const float l = L[tok * 65 + e];
      if (l > v1) { v2 = v1; i2 = i1; v1 = l; i1 = e; }
      else if (l > v2) { v2 = l; i2 = e; }
    }
    float S = 0.f;
    for (int e = 0; e < NEXP; ++e) {
      const float ex = __expf(L[tok * 65 + e] - v1);
      L[tok * 65 + e] = ex;
      S += ex;
    }
    Sv[tok] = 1.f / S;

    const float e2  = __expf(v2 - v1);
    const float inv = 1.f / (1.f + e2);
    const size_t g = (size_t)(m0 + tok);
    out_idx[g * 2 + 0] = (float)i1;
    out_idx[g * 2 + 1] = (float)i2;
    out_w[g * 2 + 0]   = inv;
    out_w[g * 2 + 1]   = e2 * inv;
  }
  __syncthreads();

  // Coalesced probs write
  const size_t pbase = (size_t)m0 * NEXP;
#pragma unroll
  for (int r = 0; r < (MTILE * NEXP) / 256; ++r) {
    const int idx = r * 256 + tid;
    const int tok = idx >> 6, e = idx & 63;
    out_p[pbase + idx] = L[tok * 65 + e] * Sv[tok];
  }
}

extern "C" void kernel_launch(void* const* d_in, const int* in_sizes, int n_in,
                              void* d_out, int out_size, void* d_ws, size_t ws_size,
                              hipStream_t stream) {
  const float* x = (const float*)d_in[0];
  const float* W = (const float*)d_in[1];
  const int ntok = in_sizes[0] / IN_DIM_C;   // 65536

  float* out_idx = (float*)d_out;                 // [ntok,2]
  float* out_w   = out_idx + (size_t)ntok * 2;    // [ntok,2]
  float* out_p   = out_w + (size_t)ntok * 2;      // [ntok,64]

  // d_ws: W bf16 hi/lo planes, 2 * 131072 ushort = 512 KB
  ushort_t* w_hi = (ushort_t*)d_ws;
  ushort_t* w_lo = w_hi + (size_t)NEXP * IN_DIM_C;

  conv_w_kernel<<<(NEXP * IN_DIM_C) / 256, 256, 0, stream>>>(W, w_hi, w_lo);

  const int blocks = ntok / MTILE;   // 1024
  router_mfma<<<blocks, 256, 0, stream>>>(x, w_hi, w_lo, out_idx, out_w, out_p);
}